// Round 4
// baseline (6012.069 us; speedup 1.0000x reference)
//
#include <hip/hip_runtime.h>
#include <hip/hip_bf16.h>

#define Bn   8
#define Sn   1024
#define HIDn 768
#define NHn  12
#define HDn  64
#define MROWS (Bn * Sn)              // 8192
#define OUT0  ((size_t)MROWS * HIDn) // 6291456

__device__ __forceinline__ float bf2f(unsigned short u) {
    union { unsigned int i; float f; } v;
    v.i = ((unsigned int)u) << 16;
    return v.f;
}
__device__ __forceinline__ unsigned short f2bf(float f) {
    __hip_bfloat16 h = __float2bfloat16(f);
    return *reinterpret_cast<unsigned short*>(&h);
}

template <typename T> struct Ld;
template <> struct Ld<unsigned short> {
    static __device__ __forceinline__ void load8(const unsigned short* src, float* d) {
        uint4 v = *(const uint4*)src;
        const unsigned short* us = (const unsigned short*)&v;
        #pragma unroll
        for (int t = 0; t < 8; ++t) d[t] = bf2f(us[t]);
    }
    static __device__ __forceinline__ float ld1(const unsigned short* p) { return bf2f(*p); }
};
template <> struct Ld<float> {
    static __device__ __forceinline__ void load8(const float* src, float* d) {
        float4 a = *(const float4*)src;
        float4 b = *(const float4*)(src + 4);
        d[0] = a.x; d[1] = a.y; d[2] = a.z; d[3] = a.w;
        d[4] = b.x; d[5] = b.y; d[6] = b.z; d[7] = b.w;
    }
    static __device__ __forceinline__ float ld1(const float* p) { return *p; }
};

// dtype probe: even-index ushorts of fp32 data are random low-mantissa bits
// (~45% insane as bf16); of bf16 data they are sane values. flag: 1=fp32, 0=bf16.
__global__ void probe_kernel(const unsigned short* __restrict__ q, int* __restrict__ flag) {
    __shared__ int cnt;
    if (threadIdx.x == 0) cnt = 0;
    __syncthreads();
    int ins = 0;
    for (int i = threadIdx.x; i < 4096; i += 256) {
        unsigned short u = q[2 * i];
        int e = (u >> 7) & 0xFF;
        float v = bf2f(u);
        if (e == 0xFF || fabsf(v) > 1e4f) ins++;
    }
    atomicAdd(&cnt, ins);
    __syncthreads();
    if (threadIdx.x == 0) *flag = (cnt > 400) ? 1 : 0;
}

// Tiled GEMM: C = A_cat @ W + bias, optional sigmoid(gate)*(.) epilogue.
// A_cat col k: k<Ksplit from A (type TA), else from A2 (type TA2), both lda=768.
// W [K,768] type TW. C store dtype: c_fp32 ? float : bf16.
template <typename TA, typename TA2, typename TW>
__launch_bounds__(256)
__global__ void gemm_kernel(const TA*  __restrict__ A,
                            const TA2* __restrict__ A2,
                            int Ksplit, int K,
                            const TW* __restrict__ W,
                            const TW* __restrict__ bias,
                            const unsigned short* __restrict__ gate,
                            void* __restrict__ Cv, int c_fp32,
                            const int* __restrict__ flag, int mymode)
{
    if (*flag != mymode) return;

    __shared__ float As[64][33];
    __shared__ float Bs[32][64];

    const int tid = threadIdx.x;
    const int tx = tid & 15, ty = tid >> 4;
    const int n0 = blockIdx.x * 64;
    const int m0 = blockIdx.y * 64;

    const int ar = tid >> 2;          // 0..63
    const int ac = (tid & 3) * 8;     // 0,8,16,24
    const int br = tid >> 3;          // 0..31
    const int bc = (tid & 7) * 8;     // 0..56

    float acc[4][4] = {};

    for (int k0 = 0; k0 < K; k0 += 32) {
        float av[8];
        if (k0 < Ksplit) Ld<TA >::load8(A  + (size_t)(m0 + ar) * HIDn + k0 + ac, av);
        else             Ld<TA2>::load8(A2 + (size_t)(m0 + ar) * HIDn + (k0 - Ksplit) + ac, av);
        #pragma unroll
        for (int t = 0; t < 8; ++t) As[ar][ac + t] = av[t];

        float bv[8];
        Ld<TW>::load8(W + (size_t)(k0 + br) * HIDn + n0 + bc, bv);
        #pragma unroll
        for (int t = 0; t < 8; ++t) Bs[br][bc + t] = bv[t];

        __syncthreads();
        #pragma unroll
        for (int k = 0; k < 32; ++k) {
            float a[4], b[4];
            #pragma unroll
            for (int i = 0; i < 4; ++i) a[i] = As[ty + 16 * i][k];
            #pragma unroll
            for (int j = 0; j < 4; ++j) b[j] = Bs[k][tx + 16 * j];
            #pragma unroll
            for (int i = 0; i < 4; ++i)
                #pragma unroll
                for (int j = 0; j < 4; ++j)
                    acc[i][j] += a[i] * b[j];
        }
        __syncthreads();
    }

    #pragma unroll
    for (int i = 0; i < 4; ++i) {
        const int row = m0 + ty + 16 * i;
        #pragma unroll
        for (int j = 0; j < 4; ++j) {
            const int col = n0 + tx + 16 * j;
            float v = acc[i][j] + Ld<TW>::ld1(bias + col);
            if (gate) {
                float g = bf2f(gate[(size_t)row * HIDn + col]);
                v = v / (1.f + expf(-g));
            }
            const size_t idx = (size_t)row * HIDn + col;
            if (c_fp32) ((float*)Cv)[idx] = v;
            else        ((unsigned short*)Cv)[idx] = f2bf(v);
        }
    }
}

// Fused attention: one block (256 thr) per (b,h,q) row. Q/K/V bf16 ws buffers.
// Writes softmax row into d_out at element offset OUT0 + rowid*S (dtype per
// flag: 1=fp32, 0=bf16) and PV row (bf16) to Xa in [B,S,NH*HD] layout.
__launch_bounds__(256)
__global__ void attn_kernel(const unsigned short* __restrict__ Q,
                            const unsigned short* __restrict__ Kb,
                            const unsigned short* __restrict__ V,
                            const int* __restrict__ mask,
                            void* __restrict__ dout,
                            unsigned short* __restrict__ xout,
                            const int* __restrict__ flag)
{
    const int bid = blockIdx.x;      // (b*NH + h)*S + q
    const int q  = bid & (Sn - 1);
    const int bh = bid >> 10;
    const int h  = bh % NHn;
    const int b  = bh / NHn;
    const int tid = threadIdx.x;
    const int ofp32 = *flag;

    __shared__ float qs[HDn];
    __shared__ float pbuf[Sn];
    __shared__ float red[4][HDn];
    __shared__ float rtmp[8];

    const size_t rowoff = ((size_t)(b * Sn + q)) * HIDn + h * HDn;
    if (tid < 8) {
        uint4 v = *(const uint4*)(Q + rowoff + tid * 8);
        const unsigned short* us = (const unsigned short*)&v;
        #pragma unroll
        for (int t = 0; t < 8; ++t) qs[tid * 8 + t] = bf2f(us[t]);
    }
    __syncthreads();

    float sc[4];
    #pragma unroll
    for (int c = 0; c < 4; ++c) {
        const int j = tid + 256 * c;
        const unsigned short* krow = Kb + ((size_t)(b * Sn + j)) * HIDn + h * HDn;
        float dot = 0.f;
        #pragma unroll
        for (int d0 = 0; d0 < HDn; d0 += 8) {
            uint4 v = *(const uint4*)(krow + d0);
            const unsigned short* us = (const unsigned short*)&v;
            #pragma unroll
            for (int t = 0; t < 8; ++t) dot += qs[d0 + t] * bf2f(us[t]);
        }
        dot *= 0.125f;                       // 1/sqrt(64)
        if (mask[b * Sn + j] == 0) dot = -1e10f;
        sc[c] = dot;
    }

    float m = fmaxf(fmaxf(sc[0], sc[1]), fmaxf(sc[2], sc[3]));
    #pragma unroll
    for (int off = 32; off > 0; off >>= 1) m = fmaxf(m, __shfl_down(m, off));
    if ((tid & 63) == 0) rtmp[tid >> 6] = m;
    __syncthreads();
    m = fmaxf(fmaxf(rtmp[0], rtmp[1]), fmaxf(rtmp[2], rtmp[3]));

    float s = 0.f;
    #pragma unroll
    for (int c = 0; c < 4; ++c) { sc[c] = expf(sc[c] - m); s += sc[c]; }
    #pragma unroll
    for (int off = 32; off > 0; off >>= 1) s += __shfl_down(s, off);
    __syncthreads();
    if ((tid & 63) == 0) rtmp[4 + (tid >> 6)] = s;
    __syncthreads();
    s = (rtmp[4] + rtmp[5]) + (rtmp[6] + rtmp[7]);
    const float inv = 1.f / s;

    const size_t aoff = OUT0 + (size_t)bid * Sn;
    #pragma unroll
    for (int c = 0; c < 4; ++c) {
        const int j = tid + 256 * c;
        const float p = sc[c] * inv;
        pbuf[j] = p;
        if (ofp32) ((float*)dout)[aoff + j] = p;
        else       ((unsigned short*)dout)[aoff + j] = f2bf(p);
    }
    __syncthreads();

    const int d = tid & 63, chunk = tid >> 6;
    const unsigned short* vcol = V + ((size_t)b * Sn) * HIDn + h * HDn + d;
    float part = 0.f;
    for (int j = chunk * 256; j < chunk * 256 + 256; ++j)
        part += pbuf[j] * bf2f(vcol[(size_t)j * HIDn]);
    red[chunk][d] = part;
    __syncthreads();
    if (tid < HDn) {
        const float x = (red[0][tid] + red[1][tid]) + (red[2][tid] + red[3][tid]);
        xout[rowoff + tid] = f2bf(x);
    }
}

extern "C" void kernel_launch(void* const* d_in, const int* in_sizes, int n_in,
                              void* d_out, int out_size, void* d_ws, size_t ws_size,
                              hipStream_t stream)
{
    const int* mask = (const int*)d_in[3];

    char* ws = (char*)d_ws;
    const size_t SZ = (size_t)MROWS * HIDn * 2;  // 12.58 MB per bf16 [8192,768]
    unsigned short* Qb = (unsigned short*)(ws);
    unsigned short* Kb = (unsigned short*)(ws + SZ);
    unsigned short* Vb = (unsigned short*)(ws + 2 * SZ);
    unsigned short* Xa = (unsigned short*)(ws + 3 * SZ);
    int* flag = (int*)(ws + 4 * SZ);             // total ws: 50.33 MB (round-2-proven)
    unsigned short* Yb = Qb;   // dead after attn
    unsigned short* H1 = Kb;   // dead after attn

    probe_kernel<<<1, 256, 0, stream>>>((const unsigned short*)d_in[0], flag);

    dim3 gg(HIDn / 64, MROWS / 64);  // (12, 128)
    const int BIG = 1 << 30;

    // ---------- QKV projections ----------
    {   // mode 0: bf16 inputs
        typedef unsigned short T;
        gemm_kernel<T,T,T><<<gg,256,0,stream>>>((const T*)d_in[0],(const T*)d_in[0],BIG,HIDn,
            (const T*)d_in[4],(const T*)d_in[5],nullptr,Qb,0,flag,0);
        gemm_kernel<T,T,T><<<gg,256,0,stream>>>((const T*)d_in[1],(const T*)d_in[1],BIG,HIDn,
            (const T*)d_in[6],(const T*)d_in[7],nullptr,Kb,0,flag,0);
        gemm_kernel<T,T,T><<<gg,256,0,stream>>>((const T*)d_in[2],(const T*)d_in[2],BIG,HIDn,
            (const T*)d_in[8],(const T*)d_in[9],nullptr,Vb,0,flag,0);
    }
    {   // mode 1: fp32 inputs
        typedef float T;
        gemm_kernel<T,T,T><<<gg,256,0,stream>>>((const T*)d_in[0],(const T*)d_in[0],BIG,HIDn,
            (const T*)d_in[4],(const T*)d_in[5],nullptr,Qb,0,flag,1);
        gemm_kernel<T,T,T><<<gg,256,0,stream>>>((const T*)d_in[1],(const T*)d_in[1],BIG,HIDn,
            (const T*)d_in[6],(const T*)d_in[7],nullptr,Kb,0,flag,1);
        gemm_kernel<T,T,T><<<gg,256,0,stream>>>((const T*)d_in[2],(const T*)d_in[2],BIG,HIDn,
            (const T*)d_in[8],(const T*)d_in[9],nullptr,Vb,0,flag,1);
    }

    // ---------- attention (out1 dtype switched on flag inside) ----------
    attn_kernel<<<Bn * NHn * Sn, 256, 0, stream>>>(Qb, Kb, Vb, mask, d_out, Xa, flag);

    // ---------- Wo projection + FFN ----------
    {   // mode 0
        typedef unsigned short T;
        gemm_kernel<T,T,T><<<gg,256,0,stream>>>(Xa,Xa,BIG,HIDn,
            (const T*)d_in[10],(const T*)d_in[11],nullptr,Yb,0,flag,0);
        gemm_kernel<T,T,T><<<gg,256,0,stream>>>(Yb,(const T*)d_in[0],HIDn,2*HIDn,
            (const T*)d_in[12],(const T*)d_in[13],nullptr,H1,0,flag,0);
        gemm_kernel<T,T,T><<<gg,256,0,stream>>>(Yb,(const T*)d_in[0],HIDn,2*HIDn,
            (const T*)d_in[14],(const T*)d_in[15],H1,d_out,/*c_fp32=*/0,flag,0);
    }
    {   // mode 1
        typedef float T;
        gemm_kernel<unsigned short,unsigned short,T><<<gg,256,0,stream>>>(Xa,Xa,BIG,HIDn,
            (const T*)d_in[10],(const T*)d_in[11],nullptr,Yb,0,flag,1);
        gemm_kernel<unsigned short,T,T><<<gg,256,0,stream>>>(Yb,(const T*)d_in[0],HIDn,2*HIDn,
            (const T*)d_in[12],(const T*)d_in[13],nullptr,H1,0,flag,1);
        gemm_kernel<unsigned short,T,T><<<gg,256,0,stream>>>(Yb,(const T*)d_in[0],HIDn,2*HIDn,
            (const T*)d_in[14],(const T*)d_in[15],H1,d_out,/*c_fp32=*/1,flag,1);
    }
}